// Round 2
// baseline (224.469 us; speedup 1.0000x reference)
//
#include <hip/hip_runtime.h>

// Problem constants (fixed by the reference)
#define BATCH 256
#define CDIM  2048
#define HW    49
#define KDIM  16

// Workspace layout (floats): wT[2048*16] at 0, pscr[256*784] at 32768.
// pscr[b][hw][k], 64B-aligned per image (784*4 = 3136 = 49*64).

// ---------------------------------------------------------------------------
// prep: wT[c][k] = w16[k][c] * inv[k]/49   (BN scale + avgpool folded in)
//       pscr[b][hw][k] = shift[k]/49       (BN shift pre-init; conv atomicAdds)
// ---------------------------------------------------------------------------
__global__ __launch_bounds__(256) void prep_kernel(
    const float* __restrict__ w16,
    const float* __restrict__ gamma, const float* __restrict__ beta,
    const float* __restrict__ mean,  const float* __restrict__ var,
    float* __restrict__ wT, float* __restrict__ pscr)
{
    const int idx = blockIdx.x * 256 + threadIdx.x;          // grid 256 -> 65536 threads
    if (idx < CDIM * KDIM) {
        const int c = idx >> 4, k = idx & 15;
        const float inv = gamma[k] * rsqrtf(var[k] + 1e-5f) * (1.0f / 49.0f);
        wT[idx] = w16[k * CDIM + c] * inv;
    }
    for (int i = idx; i < BATCH * (HW * KDIM); i += 256 * 256) {
        const int k = i & 15;
        const float inv   = gamma[k] * rsqrtf(var[k] + 1e-5f);
        const float shift = (beta[k] - mean[k] * inv) * (1.0f / 49.0f);
        pscr[i] = shift;
    }
}

// ---------------------------------------------------------------------------
// conv: P[b][hw][k] += sum_c fm[b][c][hw] * wT[c][k]
// grid = BATCH*4 (4 blocks/CU -> 32 waves/CU), block = 512 (8 waves).
// lane = hw (49 live, 15 clamped+discarded); wave owns a 64-c strip.
// wT rows are wave-uniform -> SMEM s_load (scalar pipe), FMA uses SGPR operand.
// fm read once from HBM, bytes-exact. LDS only for the 8-wave reduction.
// ---------------------------------------------------------------------------
__global__ __launch_bounds__(512) void conv_kernel(
    const float* __restrict__ fm, const float* __restrict__ wT,
    float* __restrict__ pscr)
{
    __shared__ float red[8 * KDIM * 52];          // 26.6 KB, [wave][k][hw pad 52]

    const int tid  = threadIdx.x;
    const int b    = blockIdx.x >> 2;
    const int q    = blockIdx.x & 3;
    const int wav  = __builtin_amdgcn_readfirstlane(tid >> 6);  // force wave-uniform
    const int lane = tid & 63;
    const int hwi  = lane < HW ? lane : HW - 1;   // clamp; lanes >=49 compute garbage, discarded
    const int cbase = q * 512 + wav * 64;

    const float*  __restrict__ fmb = fm + (size_t)b * CDIM * HW;
    const float4* __restrict__ wt4 = (const float4*)wT;

    float acc[KDIM];
    #pragma unroll
    for (int k = 0; k < KDIM; ++k) acc[k] = 0.f;

    #pragma unroll 2
    for (int g = 0; g < 64; g += 8) {
        float f[8];
        #pragma unroll
        for (int u = 0; u < 8; ++u)
            f[u] = fmb[(size_t)(cbase + g + u) * HW + hwi];
        #pragma unroll
        for (int u = 0; u < 8; ++u) {
            const int c4 = (cbase + g + u) * 4;
            const float4 w0 = wt4[c4 + 0];        // uniform -> s_load
            const float4 w1 = wt4[c4 + 1];
            const float4 w2 = wt4[c4 + 2];
            const float4 w3 = wt4[c4 + 3];
            const float fv = f[u];
            acc[0]  += w0.x * fv; acc[1]  += w0.y * fv; acc[2]  += w0.z * fv; acc[3]  += w0.w * fv;
            acc[4]  += w1.x * fv; acc[5]  += w1.y * fv; acc[6]  += w1.z * fv; acc[7]  += w1.w * fv;
            acc[8]  += w2.x * fv; acc[9]  += w2.y * fv; acc[10] += w2.z * fv; acc[11] += w2.w * fv;
            acc[12] += w3.x * fv; acc[13] += w3.y * fv; acc[14] += w3.z * fv; acc[15] += w3.w * fv;
        }
    }

    // reduce the 8 wave-partials in LDS, then one atomicAdd per (hw,k)
    if (lane < HW) {
        #pragma unroll
        for (int k = 0; k < KDIM; ++k)
            red[wav * (KDIM * 52) + k * 52 + lane] = acc[k];
    }
    __syncthreads();
    for (int j = tid; j < HW * KDIM; j += 512) {
        const int k = j / HW, hw = j - k * HW;
        float s = 0.f;
        #pragma unroll
        for (int w = 0; w < 8; ++w) s += red[w * (KDIM * 52) + k * 52 + hw];
        atomicAdd(&pscr[(size_t)b * (HW * KDIM) + hw * KDIM + k], s);
    }
}

// ---------------------------------------------------------------------------
// bp: out[b][k][c] = sum_hw P[b][hw][k] * fm[b][c][hw]
// grid = BATCH*2, block = 256. Thread owns one c per 256-c chunk (4 chunks).
// fm chunk staged via LDS (coalesced in, odd-stride conflict-free out).
// P is block-uniform and never stored by this kernel -> compiler emits s_load;
// the 16 FMAs/hw take the P value as the SGPR operand. fm re-read hits LLC.
// ---------------------------------------------------------------------------
__global__ __launch_bounds__(256) void bp_kernel(
    const float* __restrict__ fm, const float* __restrict__ pscr,
    float* __restrict__ out)
{
    __shared__ __align__(16) float fs[256 * HW];  // 50 KB

    const int tid  = threadIdx.x;
    const int b    = blockIdx.x >> 1;
    const int half = blockIdx.x & 1;

    const float*  __restrict__ fmb = fm + (size_t)b * CDIM * HW;
    const float4* __restrict__ P4  = (const float4*)(pscr + (size_t)b * (HW * KDIM));

    for (int ch = 0; ch < 4; ++ch) {
        const int cb = half * 1024 + ch * 256;
        __syncthreads();                          // previous chunk's reads done
        {
            const float4* src = (const float4*)(fmb + (size_t)cb * HW);
            float4* dst = (float4*)fs;
            for (int i = tid; i < (256 * HW) / 4; i += 256) dst[i] = src[i];
        }
        __syncthreads();

        float acc[KDIM];
        #pragma unroll
        for (int k = 0; k < KDIM; ++k) acc[k] = 0.f;

        const float* row = fs + tid * HW;         // stride 49 (odd) -> 2-way banks, free
        #pragma unroll 7
        for (int hw = 0; hw < HW; ++hw) {
            const float fv = row[hw];
            const float4 p0 = P4[hw * 4 + 0];     // uniform -> s_load_dwordx4/x16
            const float4 p1 = P4[hw * 4 + 1];
            const float4 p2 = P4[hw * 4 + 2];
            const float4 p3 = P4[hw * 4 + 3];
            acc[0]  += p0.x * fv; acc[1]  += p0.y * fv; acc[2]  += p0.z * fv; acc[3]  += p0.w * fv;
            acc[4]  += p1.x * fv; acc[5]  += p1.y * fv; acc[6]  += p1.z * fv; acc[7]  += p1.w * fv;
            acc[8]  += p2.x * fv; acc[9]  += p2.y * fv; acc[10] += p2.z * fv; acc[11] += p2.w * fv;
            acc[12] += p3.x * fv; acc[13] += p3.y * fv; acc[14] += p3.z * fv; acc[15] += p3.w * fv;
        }

        float* ob = out + (size_t)b * (KDIM * CDIM) + cb + tid;
        #pragma unroll
        for (int k = 0; k < KDIM; ++k) ob[k * CDIM] = acc[k];
    }
}

extern "C" void kernel_launch(void* const* d_in, const int* in_sizes, int n_in,
                              void* d_out, int out_size, void* d_ws, size_t ws_size,
                              hipStream_t stream) {
    const float* fm    = (const float*)d_in[0];
    const float* w16   = (const float*)d_in[1];
    const float* gamma = (const float*)d_in[2];
    const float* beta  = (const float*)d_in[3];
    const float* mean  = (const float*)d_in[4];
    const float* var   = (const float*)d_in[5];
    float* out  = (float*)d_out;
    float* wT   = (float*)d_ws;                   // 32768 floats (128 KB)
    float* pscr = (float*)d_ws + CDIM * KDIM;     // 256*784 floats (~784 KB)

    prep_kernel<<<256, 256, 0, stream>>>(w16, gamma, beta, mean, var, wT, pscr);
    conv_kernel<<<BATCH * 4, 512, 0, stream>>>(fm, wT, pscr);
    bp_kernel<<<BATCH * 2, 256, 0, stream>>>(fm, pscr, out);
}

// Round 3
// 222.453 us; speedup vs baseline: 1.0091x; 1.0091x over previous
//
#include <hip/hip_runtime.h>

// Problem constants (fixed by the reference)
#define BATCH 256
#define CDIM  2048
#define HW    49
#define KDIM  16

// Workspace layout (floats): wT[2048*16] at 0, pscr[256*784] at 32768.

// ---------------------------------------------------------------------------
// prep: wT[c][k] = w16[k][c] * inv[k]/49   (BN scale + avgpool folded in)
//       pscr[b][hw][k] = shift[k]/49       (BN shift pre-init; conv atomicAdds)
// ---------------------------------------------------------------------------
__global__ __launch_bounds__(256) void prep_kernel(
    const float* __restrict__ w16,
    const float* __restrict__ gamma, const float* __restrict__ beta,
    const float* __restrict__ mean,  const float* __restrict__ var,
    float* __restrict__ wT, float* __restrict__ pscr)
{
    const int idx = blockIdx.x * 256 + threadIdx.x;          // grid 256 -> 65536 threads
    if (idx < CDIM * KDIM) {
        const int c = idx >> 4, k = idx & 15;
        const float inv = gamma[k] * rsqrtf(var[k] + 1e-5f) * (1.0f / 49.0f);
        wT[idx] = w16[k * CDIM + c] * inv;
    }
    for (int i = idx; i < BATCH * (HW * KDIM); i += 256 * 256) {
        const int k = i & 15;
        const float inv   = gamma[k] * rsqrtf(var[k] + 1e-5f);
        const float shift = (beta[k] - mean[k] * inv) * (1.0f / 49.0f);
        pscr[i] = shift;
    }
}

// ---------------------------------------------------------------------------
// conv: P[b][hw][k] += sum_c fm[b][c][hw] * wT[c][k]
// grid = BATCH*4, block = 512 (8 waves). lane = hw (49 live).
// Weights staged in LDS once (32 KB) and read at wave-uniform addresses:
// broadcast, conflict-free, and on lgkmcnt -- decoupled from the f-loads'
// vmcnt queue, so f prefetches stay in flight across the whole 16-c batch.
// ---------------------------------------------------------------------------
__global__ __launch_bounds__(512) void conv_kernel(
    const float* __restrict__ fm, const float* __restrict__ wT,
    float* __restrict__ pscr)
{
    __shared__ __align__(16) float wL[512 * KDIM];   // [c][k] strip, 32 KB
    __shared__ float red[8 * KDIM * 52];             // 26.6 KB, [wave][k][hw pad 52]

    const int tid  = threadIdx.x;
    const int b    = blockIdx.x >> 2;
    const int q    = blockIdx.x & 3;
    const int wav  = __builtin_amdgcn_readfirstlane(tid >> 6);
    const int lane = tid & 63;
    const int hwi  = lane < HW ? lane : HW - 1;      // clamp; lanes >=49 discarded

    // stage the block's 512-c weight strip: 8192 floats, coalesced float4
    {
        const float4* src = (const float4*)(wT + q * 512 * KDIM);
        float4* dst = (float4*)wL;
        #pragma unroll 4
        for (int i = tid; i < (512 * KDIM) / 4; i += 512) dst[i] = src[i];
    }
    __syncthreads();

    float acc[KDIM];
    #pragma unroll
    for (int k = 0; k < KDIM; ++k) acc[k] = 0.f;

    // lane pointer for this wave's 64-c strip (one size_t computation total)
    const float* fp = fm + (size_t)b * (CDIM * HW) + (size_t)(q * 512 + wav * 64) * HW + hwi;

    for (int g = 0; g < 64; g += 16) {
        float f[16];
        #pragma unroll
        for (int u = 0; u < 16; ++u)                 // 16 global dwords, vmcnt-only
            f[u] = fp[(g + u) * HW];
        #pragma unroll
        for (int u = 0; u < 16; ++u) {
            const float4* wrow = (const float4*)&wL[(wav * 64 + g + u) * KDIM];
            const float4 w0 = wrow[0];               // uniform addr -> LDS broadcast (lgkm)
            const float4 w1 = wrow[1];
            const float4 w2 = wrow[2];
            const float4 w3 = wrow[3];
            const float fv = f[u];
            acc[0]  += w0.x * fv; acc[1]  += w0.y * fv; acc[2]  += w0.z * fv; acc[3]  += w0.w * fv;
            acc[4]  += w1.x * fv; acc[5]  += w1.y * fv; acc[6]  += w1.z * fv; acc[7]  += w1.w * fv;
            acc[8]  += w2.x * fv; acc[9]  += w2.y * fv; acc[10] += w2.z * fv; acc[11] += w2.w * fv;
            acc[12] += w3.x * fv; acc[13] += w3.y * fv; acc[14] += w3.z * fv; acc[15] += w3.w * fv;
        }
    }

    // reduce the 8 wave-partials in LDS, then one atomicAdd per (hw,k)
    if (lane < HW) {
        #pragma unroll
        for (int k = 0; k < KDIM; ++k)
            red[wav * (KDIM * 52) + k * 52 + lane] = acc[k];
    }
    __syncthreads();
    for (int j = tid; j < HW * KDIM; j += 512) {
        const int k = j / HW, hw = j - k * HW;
        float s = 0.f;
        #pragma unroll
        for (int w = 0; w < 8; ++w) s += red[w * (KDIM * 52) + k * 52 + hw];
        atomicAdd(&pscr[(size_t)b * (HW * KDIM) + hw * KDIM + k], s);
    }
}

// ---------------------------------------------------------------------------
// bp: out[b][k][c] = sum_hw P[b][hw][k] * fm[b][c][hw]
// (unchanged from round 2 -- keeps the A/B on conv clean)
// ---------------------------------------------------------------------------
__global__ __launch_bounds__(256) void bp_kernel(
    const float* __restrict__ fm, const float* __restrict__ pscr,
    float* __restrict__ out)
{
    __shared__ __align__(16) float fs[256 * HW];  // 50 KB

    const int tid  = threadIdx.x;
    const int b    = blockIdx.x >> 1;
    const int half = blockIdx.x & 1;

    const float*  __restrict__ fmb = fm + (size_t)b * CDIM * HW;
    const float4* __restrict__ P4  = (const float4*)(pscr + (size_t)b * (HW * KDIM));

    for (int ch = 0; ch < 4; ++ch) {
        const int cb = half * 1024 + ch * 256;
        __syncthreads();                          // previous chunk's reads done
        {
            const float4* src = (const float4*)(fmb + (size_t)cb * HW);
            float4* dst = (float4*)fs;
            for (int i = tid; i < (256 * HW) / 4; i += 256) dst[i] = src[i];
        }
        __syncthreads();

        float acc[KDIM];
        #pragma unroll
        for (int k = 0; k < KDIM; ++k) acc[k] = 0.f;

        const float* row = fs + tid * HW;         // stride 49 (odd) -> 2-way banks, free
        #pragma unroll 7
        for (int hw = 0; hw < HW; ++hw) {
            const float fv = row[hw];
            const float4 p0 = P4[hw * 4 + 0];
            const float4 p1 = P4[hw * 4 + 1];
            const float4 p2 = P4[hw * 4 + 2];
            const float4 p3 = P4[hw * 4 + 3];
            acc[0]  += p0.x * fv; acc[1]  += p0.y * fv; acc[2]  += p0.z * fv; acc[3]  += p0.w * fv;
            acc[4]  += p1.x * fv; acc[5]  += p1.y * fv; acc[6]  += p1.z * fv; acc[7]  += p1.w * fv;
            acc[8]  += p2.x * fv; acc[9]  += p2.y * fv; acc[10] += p2.z * fv; acc[11] += p2.w * fv;
            acc[12] += p3.x * fv; acc[13] += p3.y * fv; acc[14] += p3.z * fv; acc[15] += p3.w * fv;
        }

        float* ob = out + (size_t)b * (KDIM * CDIM) + cb + tid;
        #pragma unroll
        for (int kk = 0; kk < 16; ++kk) ob[kk * CDIM] = acc[kk];
    }
}

extern "C" void kernel_launch(void* const* d_in, const int* in_sizes, int n_in,
                              void* d_out, int out_size, void* d_ws, size_t ws_size,
                              hipStream_t stream) {
    const float* fm    = (const float*)d_in[0];
    const float* w16   = (const float*)d_in[1];
    const float* gamma = (const float*)d_in[2];
    const float* beta  = (const float*)d_in[3];
    const float* mean  = (const float*)d_in[4];
    const float* var   = (const float*)d_in[5];
    float* out  = (float*)d_out;
    float* wT   = (float*)d_ws;                   // 32768 floats (128 KB)
    float* pscr = (float*)d_ws + CDIM * KDIM;     // 256*784 floats (~784 KB)

    prep_kernel<<<256, 256, 0, stream>>>(w16, gamma, beta, mean, var, wT, pscr);
    conv_kernel<<<BATCH * 4, 512, 0, stream>>>(fm, wT, pscr);
    bp_kernel<<<BATCH * 2, 256, 0, stream>>>(fm, pscr, out);
}